// Round 13
// baseline (224.010 us; speedup 1.0000x reference)
//
#include <hip/hip_runtime.h>
#include <hip/hip_bf16.h>
#include <hip/hip_cooperative_groups.h>

namespace cg = cooperative_groups;

#define EPSV  1e-5f
#define QSC   0.0625f     // C^-0.5 (natural-exp softmax)

typedef __attribute__((ext_vector_type(8))) __bf16 bfrag;   // MFMA A/B operand
typedef __attribute__((ext_vector_type(4))) float  f32x4;
typedef __attribute__((ext_vector_type(8))) short  s16x8;
typedef __attribute__((ext_vector_type(4))) short  s16x4;

static __device__ __forceinline__ short f2b(float f) {
    __hip_bfloat16 h = __float2bfloat16(f);
    return __builtin_bit_cast(short, h);
}

// async global->LDS, 16B per lane; LDS dest = wave-uniform base + lane*16
#define GLDS16(SRC, DST) __builtin_amdgcn_global_load_lds( \
    (__attribute__((address_space(1))) void*)(SRC),        \
    (__attribute__((address_space(3))) void*)(DST), 16, 0, 0)

// ---------------------------------------------------------------------------
// MEGA kernel: 256 blocks x 512 threads, cooperative.
//   Phase 1: GN partial sums (t<256) + weight transpose bf16 (t>=256)
//   Phase 2: GN-finalize + QKV projection (two 64-row halves per block)
//   Phase 3: flash attention (r5-proven loop) + fused output projection
// LDS pool L (144 KB) re-carved per phase.
// ---------------------------------------------------------------------------
__global__ __launch_bounds__(512) void mega(
    const float* __restrict__ x,
    const float* __restrict__ gns, const float* __restrict__ gnb,
    const float* __restrict__ wq,  const float* __restrict__ bq,
    const float* __restrict__ wk,  const float* __restrict__ bk,
    const float* __restrict__ wv,  const float* __restrict__ bv,
    const float* __restrict__ wo,  const float* __restrict__ bo,
    float* __restrict__ part, short* __restrict__ wt,
    short* __restrict__ qb, short* __restrict__ kb, short* __restrict__ vtb,
    float* __restrict__ out)
{
    __shared__ __align__(1024) short L[73728];   // 144 KB
    cg::grid_group grid = cg::this_grid();

    const int bid  = blockIdx.x;
    const int t    = threadIdx.x;
    const int w    = t >> 6, lane = t & 63;
    const int lr   = lane & 15, lh = lane >> 4;

    // ===================== PHASE 1: GN partials + weight prep =====================
    {
        if (t < 256) {
            const int b = bid >> 3, ch = bid & 7;
            const int c4 = t & 63, rr = t >> 6;
            float s1 = 0.f, s2 = 0.f;
            for (int i = 0; i < 32; ++i) {
                const int pos = ch * 128 + rr + (i << 2);
                const f32x4 v = *reinterpret_cast<const f32x4*>(
                    x + (((b << 10) + pos) << 8) + (c4 << 2));
                s1 += v[0] + v[1] + v[2] + v[3];
                s2 += v[0]*v[0] + v[1]*v[1] + v[2]*v[2] + v[3]*v[3];
            }
            float* ls1 = (float*)L;
            float* ls2 = (float*)L + 256;
            ls1[t] = s1; ls2[t] = s2;
        } else {
            // transpose 4 weight elems per thread: wt[z][n][k] = w[k][n] (bf16)
            const int u  = (bid << 8) + (t - 256);   // 0..65535
            const int z  = u >> 14;
            const int r  = u & 16383;
            const int n  = r >> 6;
            const int k4 = (r & 63) << 2;
            const float* wsrc = (z == 0) ? wq : (z == 1) ? wk : (z == 2) ? wv : wo;
            s16x4 o;
            for (int e = 0; e < 4; ++e) o[e] = f2b(wsrc[(k4 + e) * 256 + n]);
            *reinterpret_cast<s16x4*>(&wt[((z * 256 + n) << 8) + k4]) = o;
        }
        __syncthreads();
        if (t < 32) {
            float* ls1 = (float*)L;
            float* ls2 = (float*)L + 256;
            float a1 = 0.f, a2 = 0.f;
            for (int r2 = 0; r2 < 4; ++r2)
                for (int e = 0; e < 2; ++e) {
                    const int idx = r2 * 64 + t * 2 + e;
                    a1 += ls1[idx]; a2 += ls2[idx];
                }
            const int b = bid >> 3, ch = bid & 7;
            part[((b * 8 + ch) * 32 + t) * 2 + 0] = a1;
            part[((b * 8 + ch) * 32 + t) * 2 + 1] = a2;
        }
    }
    grid.sync();

    // ===================== PHASE 2: GN-finalize + QKV =====================
    {
        const int half = w >> 2, w4 = w & 3;
        const int b    = bid >> 3;
        const int m0   = (bid << 7) + (half << 6);   // this half's 64 rows
        // LDS carve: At0 [0..16895], At1 [16896..33791], floats at 33792
        float* gm = (float*)(L + 33792);
        float* gr = gm + 32;
        float* sA = gr + 32;
        float* sB = sA + 256;

        if (t < 32) {
            float s1 = 0.f, s2 = 0.f;
            for (int ch = 0; ch < 8; ++ch) {
                s1 += part[((b * 8 + ch) * 32 + t) * 2 + 0];
                s2 += part[((b * 8 + ch) * 32 + t) * 2 + 1];
            }
            const float mean = s1 * (1.f / 8192.f);
            const float var  = s2 * (1.f / 8192.f) - mean * mean;
            gm[t] = mean;
            gr[t] = rsqrtf(var + EPSV);
        }
        __syncthreads();
        if (t < 256) {
            const float a = gr[t >> 3] * gns[t];
            sA[t] = a;
            sB[t] = gnb[t] - gm[t >> 3] * a;
        }
        __syncthreads();

        // A-tiles: threads 0..255 stage half 0, 256..511 stage half 1
        {
            const int hh = t >> 8;
            const int tt = t & 255;
            const int r = tt >> 2, q4 = tt & 3;
            short* Ath = L + hh * 16896;
            const float* xrow = x + ((bid << 7) + (hh << 6) + r) * 256;
            for (int i = 0; i < 16; ++i) {
                const int c0 = (q4 + 4 * i) * 4;
                const f32x4 v  = *reinterpret_cast<const f32x4*>(xrow + c0);
                const f32x4 aa = *reinterpret_cast<const f32x4*>(&sA[c0]);
                const f32x4 bb = *reinterpret_cast<const f32x4*>(&sB[c0]);
                s16x4 o;
                for (int j = 0; j < 4; ++j) o[j] = f2b(v[j] * aa[j] + bb[j]);
                *reinterpret_cast<s16x4*>(&Ath[r * 264 + c0]) = o;
            }
        }
        __syncthreads();

        short* At = L + half * 16896;
        for (int z = 0; z < 3; ++z) {
            f32x4 acc[4][4];
            for (int mi = 0; mi < 4; ++mi)
                for (int ni = 0; ni < 4; ++ni) acc[mi][ni] = (f32x4){0.f, 0.f, 0.f, 0.f};
            const short* wz = wt + z * 65536 + (w4 * 64 + lr) * 256 + lh * 8;
#pragma unroll
            for (int kt = 0; kt < 8; ++kt) {
                bfrag bf[4];
#pragma unroll
                for (int ni = 0; ni < 4; ++ni)
                    bf[ni] = *reinterpret_cast<const bfrag*>(wz + ni * 4096 + kt * 32);
                bfrag af[4];
#pragma unroll
                for (int mi = 0; mi < 4; ++mi)
                    af[mi] = *reinterpret_cast<const bfrag*>(&At[(mi * 16 + lr) * 264 + kt * 32 + lh * 8]);
#pragma unroll
                for (int ni = 0; ni < 4; ++ni)
#pragma unroll
                    for (int mi = 0; mi < 4; ++mi)
                        acc[mi][ni] = __builtin_amdgcn_mfma_f32_16x16x32_bf16(af[mi], bf[ni], acc[mi][ni], 0, 0, 0);
            }
            if (z == 2) {
                for (int ni = 0; ni < 4; ++ni) {
                    const int col = w4 * 64 + ni * 16 + lr;
                    const float bb = bv[col];
                    for (int mi = 0; mi < 4; ++mi) {
                        const int pos = (m0 & 1023) + mi * 16 + lh * 4;
                        s16x4 ov;
                        for (int j = 0; j < 4; ++j) ov[j] = f2b(acc[mi][ni][j] + bb);
                        *reinterpret_cast<s16x4*>(&vtb[(((b << 8) + col) << 10) + pos]) = ov;
                    }
                }
            } else {
                short* outp = (z == 0) ? qb : kb;
                const float* bias = (z == 0) ? bq : bk;
                const float s = (z == 0) ? QSC : 1.0f;
                for (int ni = 0; ni < 4; ++ni) {
                    const int col = w4 * 64 + ni * 16 + lr;
                    const float bsc = bias[col] * s;
                    for (int mi = 0; mi < 4; ++mi) {
                        const int row = m0 + mi * 16 + lh * 4;
                        for (int j = 0; j < 4; ++j)
                            outp[(row + j) * 256 + col] = f2b(acc[mi][ni][j] * s + bsc);
                    }
                }
            }
        }
    }
    grid.sync();

    // ===================== PHASE 3: attention + fused oproj =====================
    {
        int bid3 = ((bid & 7) << 5) | (bid >> 3);   // XCD swizzle
        const int b = bid3 >> 3, qt = bid3 & 7;
        const int qr0 = qt * 128 + w * 16;
        const int sw = lr & 7;

        bfrag qf[8];
        {
            const short* qp = qb + (((b << 10) + qr0 + lr) << 8) + lh * 8;
#pragma unroll
            for (int ks = 0; ks < 8; ++ks)
                qf[ks] = *reinterpret_cast<const bfrag*>(qp + ks * 32);
        }

        const short* kbase = kb + ((long)b << 18);
        const short* vbase = vtb + ((long)b << 18);
        short* plw = L + 65536 + (w << 10);

        auto stageK = [&](int kt_, int buf) {
#pragma unroll
            for (int t2 = 0; t2 < 4; ++t2) {
                const int rbase = w * 8 + t2 * 2;
                const int r  = rbase + (lane >> 5);
                const int gs = (lane & 31) ^ (r & 7);
                GLDS16(kbase + ((kt_ * 64 + r) << 8) + (gs << 3),
                       &L[buf * 16384 + (rbase << 8)]);
            }
        };
        auto stageV = [&](int kt_, int buf) {
#pragma unroll
            for (int t2 = 0; t2 < 4; ++t2) {
                const int rbase = w * 32 + t2 * 8;
                const int r  = rbase + (lane >> 3);
                const int gs = (lane & 7) ^ (r & 7);
                GLDS16(vbase + (r << 10) + kt_ * 64 + (gs << 3),
                       &L[32768 + buf * 16384 + (rbase << 6)]);
            }
        };

        f32x4 o[16];
#pragma unroll
        for (int ci = 0; ci < 16; ++ci) o[ci] = (f32x4){0.f, 0.f, 0.f, 0.f};
        float m = -3e38f, lsum = 0.f;

        stageK(0, 0); stageV(0, 0);

        for (int kt = 0; kt < 16; ++kt) {
            const int cur = kt & 1;
            __asm__ volatile("s_barrier" ::: "memory");
            if (kt < 15) {
                stageK(kt + 1, cur ^ 1);
                stageV(kt + 1, cur ^ 1);
                __asm__ volatile("s_waitcnt vmcnt(8)" ::: "memory");
            } else {
                __asm__ volatile("s_waitcnt vmcnt(0)" ::: "memory");
            }
            __asm__ volatile("s_barrier" ::: "memory");

            // ---- S^T = K . Q
            f32x4 sacc[4];
#pragma unroll
            for (int ni = 0; ni < 4; ++ni) sacc[ni] = (f32x4){0.f, 0.f, 0.f, 0.f};
            __builtin_amdgcn_s_setprio(1);
#pragma unroll
            for (int ks = 0; ks < 8; ++ks) {
#pragma unroll
                for (int ni = 0; ni < 4; ++ni) {
                    const int row = ni * 16 + lr;
                    const bfrag kf = *reinterpret_cast<const bfrag*>(
                        &L[cur * 16384 + (row << 8) + ((((ks << 2) + lh) ^ sw) << 3)]);
                    sacc[ni] = __builtin_amdgcn_mfma_f32_16x16x32_bf16(kf, qf[ks], sacc[ni], 0, 0, 0);
                }
            }
            __builtin_amdgcn_s_setprio(0);

            // ---- online softmax (per-lane q-row = lr)
            float rm = fmaxf(fmaxf(sacc[0][0], sacc[0][1]), fmaxf(sacc[0][2], sacc[0][3]));
#pragma unroll
            for (int ni = 1; ni < 4; ++ni)
                rm = fmaxf(rm, fmaxf(fmaxf(sacc[ni][0], sacc[ni][1]),
                                     fmaxf(sacc[ni][2], sacc[ni][3])));
            rm = fmaxf(rm, __shfl_xor(rm, 16));
            rm = fmaxf(rm, __shfl_xor(rm, 32));

            const bool grow = __any(rm > m);
            float p[4][4];
            float rs = 0.f;
            if (grow) {
                const float mn = fmaxf(m, rm);
                const float sc = __expf(m - mn);
                m = mn;
#pragma unroll
                for (int ni = 0; ni < 4; ++ni)
#pragma unroll
                    for (int r2 = 0; r2 < 4; ++r2) {
                        p[ni][r2] = __expf(sacc[ni][r2] - mn);
                        rs += p[ni][r2];
                    }
                rs += __shfl_xor(rs, 16);
                rs += __shfl_xor(rs, 32);
                lsum = lsum * sc + rs;
                float scb[4];
#pragma unroll
                for (int j = 0; j < 4; ++j) scb[j] = __shfl(sc, lh * 4 + j);
#pragma unroll
                for (int ci = 0; ci < 16; ++ci)
#pragma unroll
                    for (int j = 0; j < 4; ++j) o[ci][j] *= scb[j];
            } else {
#pragma unroll
                for (int ni = 0; ni < 4; ++ni)
#pragma unroll
                    for (int r2 = 0; r2 < 4; ++r2) {
                        p[ni][r2] = __expf(sacc[ni][r2] - m);
                        rs += p[ni][r2];
                    }
                rs += __shfl_xor(rs, 16);
                rs += __shfl_xor(rs, 32);
                lsum += rs;
            }

            // ---- stage P
#pragma unroll
            for (int ni = 0; ni < 4; ++ni) {
                s16x4 pw;
#pragma unroll
                for (int r2 = 0; r2 < 4; ++r2) pw[r2] = f2b(p[ni][r2]);
                const int gc = (ni << 1) + (lh >> 1);
                const int ad = (lr << 6) + ((gc ^ sw) << 3) + ((lh & 1) << 2);
                *reinterpret_cast<s16x4*>(&plw[ad]) = pw;
            }
            const bfrag pa0 = *reinterpret_cast<const bfrag*>(
                &plw[(lr << 6) + ((lh ^ sw) << 3)]);
            const bfrag pa1 = *reinterpret_cast<const bfrag*>(
                &plw[(lr << 6) + (((4 + lh) ^ sw) << 3)]);

            // ---- O += P . V
            __builtin_amdgcn_s_setprio(1);
#pragma unroll
            for (int ci = 0; ci < 16; ++ci) {
                const int row = (ci << 4) + lr;
                const bfrag vb0 = *reinterpret_cast<const bfrag*>(
                    &L[32768 + cur * 16384 + (row << 6) + ((lh ^ sw) << 3)]);
                const bfrag vb1 = *reinterpret_cast<const bfrag*>(
                    &L[32768 + cur * 16384 + (row << 6) + (((4 + lh) ^ sw) << 3)]);
                o[ci] = __builtin_amdgcn_mfma_f32_16x16x32_bf16(pa0, vb0, o[ci], 0, 0, 0);
                o[ci] = __builtin_amdgcn_mfma_f32_16x16x32_bf16(pa1, vb1, o[ci], 0, 0, 0);
            }
            __builtin_amdgcn_s_setprio(0);
        }

        float invb[4];
#pragma unroll
        for (int j = 0; j < 4; ++j) invb[j] = 1.0f / __shfl(lsum, lh * 4 + j);

        // ---------- fused output projection ----------
        __syncthreads();   // Kt/Vt/Pl dead -> reuse L as Ot[128][264]

        // prefetch x residual (64 floats/lane) so HBM latency hides under GEMM
        const int m0r = (b << 10) + qt * 128;
        float xr[2][8][4];
#pragma unroll
        for (int ni = 0; ni < 2; ++ni) {
            const int col = w * 32 + ni * 16 + lr;
#pragma unroll
            for (int mi = 0; mi < 8; ++mi)
#pragma unroll
                for (int j = 0; j < 4; ++j)
                    xr[ni][mi][j] = x[(m0r + mi * 16 + lh * 4 + j) * 256 + col];
        }

        // write normalized O (bf16) into Ot; wave w owns local rows w*16..+15
#pragma unroll
        for (int j = 0; j < 4; ++j) {
            const int rloc = w * 16 + lh * 4 + j;
#pragma unroll
            for (int ci = 0; ci < 16; ++ci)
                L[rloc * 264 + (ci << 4) + lr] = f2b(o[ci][j] * invb[j]);
        }
        __syncthreads();

        // per-block GEMM: Ot[128][256] x Wo^T; 8 waves x 32 cols
        const short* wto = wt + 3 * 65536;
        f32x4 acc[8][2];
#pragma unroll
        for (int mi = 0; mi < 8; ++mi) {
            acc[mi][0] = (f32x4){0.f, 0.f, 0.f, 0.f};
            acc[mi][1] = (f32x4){0.f, 0.f, 0.f, 0.f};
        }
        const short* wz = wto + (w * 32 + lr) * 256 + lh * 8;
#pragma unroll
        for (int kt = 0; kt < 8; ++kt) {
            bfrag bf[2];
#pragma unroll
            for (int ni = 0; ni < 2; ++ni)
                bf[ni] = *reinterpret_cast<const bfrag*>(wz + ni * 4096 + kt * 32);
            bfrag af[8];
#pragma unroll
            for (int mi = 0; mi < 8; ++mi)
                af[mi] = *reinterpret_cast<const bfrag*>(
                    &L[(mi * 16 + lr) * 264 + kt * 32 + lh * 8]);
#pragma unroll
            for (int ni = 0; ni < 2; ++ni)
#pragma unroll
                for (int mi = 0; mi < 8; ++mi)
                    acc[mi][ni] = __builtin_amdgcn_mfma_f32_16x16x32_bf16(af[mi], bf[ni], acc[mi][ni], 0, 0, 0);
        }

#pragma unroll
        for (int ni = 0; ni < 2; ++ni) {
            const int col = w * 32 + ni * 16 + lr;
            const float bb = bo[col];
#pragma unroll
            for (int mi = 0; mi < 8; ++mi) {
                const int row = m0r + mi * 16 + lh * 4;
#pragma unroll
                for (int j = 0; j < 4; ++j)
                    out[(row + j) * 256 + col] = acc[mi][ni][j] + bb + xr[ni][mi][j];
            }
        }
    }
}

// ---------------------------------------------------------------------------
extern "C" void kernel_launch(void* const* d_in, const int* in_sizes, int n_in,
                              void* d_out, int out_size, void* d_ws, size_t ws_size,
                              hipStream_t stream) {
    const float* x   = (const float*)d_in[0];
    const float* gns = (const float*)d_in[1];
    const float* gnb = (const float*)d_in[2];
    const float* Wq  = (const float*)d_in[3];
    const float* bq  = (const float*)d_in[4];
    const float* Wk  = (const float*)d_in[5];
    const float* bk  = (const float*)d_in[6];
    const float* Wv  = (const float*)d_in[7];
    const float* bv  = (const float*)d_in[8];
    const float* Wo  = (const float*)d_in[9];
    const float* bo  = (const float*)d_in[10];
    float* out = (float*)d_out;

    char* ws = (char*)d_ws;
    short* wt   = (short*)(ws);
    float* part = (float*)(ws + 524288);
    const size_t MB16 = 16777216;
    short* qb  = (short*)(ws + (1 << 20));
    short* kb  = (short*)(ws + (1 << 20) + MB16);
    short* vtb = (short*)(ws + (1 << 20) + 2 * MB16);

    void* args[] = {
        (void*)&x, (void*)&gns, (void*)&gnb,
        (void*)&Wq, (void*)&bq, (void*)&Wk, (void*)&bk,
        (void*)&Wv, (void*)&bv, (void*)&Wo, (void*)&bo,
        (void*)&part, (void*)&wt, (void*)&qb, (void*)&kb, (void*)&vtb,
        (void*)&out
    };
    hipLaunchCooperativeKernel((void*)mega, dim3(256), dim3(512), args, 0, stream);
}

// Round 14
// 131.383 us; speedup vs baseline: 1.7050x; 1.7050x over previous
//
#include <hip/hip_runtime.h>
#include <hip/hip_bf16.h>

#define EPSV  1e-5f
#define QSC   0.0625f     // C^-0.5 (natural-exp softmax)

typedef __attribute__((ext_vector_type(8))) __bf16 bfrag;   // MFMA A/B operand
typedef __attribute__((ext_vector_type(4))) float  f32x4;
typedef __attribute__((ext_vector_type(8))) short  s16x8;
typedef __attribute__((ext_vector_type(4))) short  s16x4;

static __device__ __forceinline__ short f2b(float f) {
    __hip_bfloat16 h = __float2bfloat16(f);
    return __builtin_bit_cast(short, h);
}

// async global->LDS, 16B per lane; LDS dest = wave-uniform base + lane*16
#define GLDS16(SRC, DST) __builtin_amdgcn_global_load_lds( \
    (__attribute__((address_space(1))) void*)(SRC),        \
    (__attribute__((address_space(3))) void*)(DST), 16, 0, 0)

// ---------------------------------------------------------------------------
// K1: GroupNorm partial sums (blocks 0..255)  +  weight transpose to bf16
//     (blocks 256..1279) fused into one launch.
// ---------------------------------------------------------------------------
__global__ __launch_bounds__(256) void gn_part_prep(const float* __restrict__ x,
                                                    float* __restrict__ part,
                                                    const float* __restrict__ wq,
                                                    const float* __restrict__ wk,
                                                    const float* __restrict__ wv,
                                                    const float* __restrict__ wo,
                                                    short* __restrict__ wt) {
    if (blockIdx.x >= 256) {
        const int bb = blockIdx.x - 256;
        const int z = bb >> 8;
        const int n = bb & 255;
        const int k = threadIdx.x;
        const float* w = (z == 0) ? wq : (z == 1) ? wk : (z == 2) ? wv : wo;
        wt[(z * 256 + n) * 256 + k] = f2b(w[k * 256 + n]);
        return;
    }
    const int b = blockIdx.x >> 3, ch = blockIdx.x & 7;
    const int t = threadIdx.x;
    const int c4 = t & 63;
    const int rr = t >> 6;
    float s1 = 0.f, s2 = 0.f;
    for (int i = 0; i < 32; ++i) {
        const int pos = ch * 128 + rr + (i << 2);
        const f32x4 v = *reinterpret_cast<const f32x4*>(x + (((b << 10) + pos) << 8) + (c4 << 2));
        s1 += v[0] + v[1] + v[2] + v[3];
        s2 += v[0]*v[0] + v[1]*v[1] + v[2]*v[2] + v[3]*v[3];
    }
    __shared__ float ls1[256], ls2[256];
    ls1[t] = s1; ls2[t] = s2;
    __syncthreads();
    if (t < 32) {
        float a1 = 0.f, a2 = 0.f;
        for (int r2 = 0; r2 < 4; ++r2)
            for (int e = 0; e < 2; ++e) {
                const int idx = r2 * 64 + t * 2 + e;
                a1 += ls1[idx]; a2 += ls2[idx];
            }
        part[((b * 8 + ch) * 32 + t) * 2 + 0] = a1;
        part[((b * 8 + ch) * 32 + t) * 2 + 1] = a2;
    }
}

// ---------------------------------------------------------------------------
// K2: fused GN-finalize + GN-normalize + QKV projection.
// ---------------------------------------------------------------------------
__global__ __launch_bounds__(256) void qkv_gemm(const float* __restrict__ x,
                                                const float* __restrict__ part,
                                                const float* __restrict__ gns,
                                                const float* __restrict__ gnb,
                                                const short* __restrict__ wt,
                                                const float* __restrict__ bq,
                                                const float* __restrict__ bk,
                                                const float* __restrict__ bv,
                                                short* __restrict__ qo,
                                                short* __restrict__ ko,
                                                short* __restrict__ vtg) {
    __shared__ short At[64][264];
    __shared__ float gmean[32], grstd[32];
    __shared__ float sA[256], sB[256];

    const int t  = threadIdx.x;
    const int m0 = blockIdx.x * 64;
    const int b  = m0 >> 10;
    const int lane = t & 63, w = t >> 6;
    const int lr = lane & 15, lh = lane >> 4;

    if (t < 32) {
        float s1 = 0.f, s2 = 0.f;
        for (int ch = 0; ch < 8; ++ch) {
            s1 += part[((b * 8 + ch) * 32 + t) * 2 + 0];
            s2 += part[((b * 8 + ch) * 32 + t) * 2 + 1];
        }
        const float mean = s1 * (1.f / 8192.f);
        const float var  = s2 * (1.f / 8192.f) - mean * mean;
        gmean[t] = mean;
        grstd[t] = rsqrtf(var + EPSV);
    }
    __syncthreads();
    {
        const float a = grstd[t >> 3] * gns[t];
        sA[t] = a;
        sB[t] = gnb[t] - gmean[t >> 3] * a;
    }
    __syncthreads();

    {
        const int r = t >> 2, q4 = t & 3;
        const float* xrow = x + (m0 + r) * 256;
        for (int i = 0; i < 16; ++i) {
            const int c0 = (q4 + 4 * i) * 4;
            const f32x4 v  = *reinterpret_cast<const f32x4*>(xrow + c0);
            const f32x4 aa = *reinterpret_cast<const f32x4*>(&sA[c0]);
            const f32x4 bb = *reinterpret_cast<const f32x4*>(&sB[c0]);
            s16x4 o;
            for (int j = 0; j < 4; ++j) o[j] = f2b(v[j] * aa[j] + bb[j]);
            *reinterpret_cast<s16x4*>(&At[r][c0]) = o;
        }
    }
    __syncthreads();

    for (int z = 0; z < 3; ++z) {
        f32x4 acc[4][4];
        for (int mi = 0; mi < 4; ++mi)
            for (int ni = 0; ni < 4; ++ni) acc[mi][ni] = (f32x4){0.f, 0.f, 0.f, 0.f};
        const short* wz = wt + z * 65536 + (w * 64 + lr) * 256 + lh * 8;
#pragma unroll
        for (int kt = 0; kt < 8; ++kt) {
            bfrag bf[4];
#pragma unroll
            for (int ni = 0; ni < 4; ++ni)
                bf[ni] = *reinterpret_cast<const bfrag*>(wz + ni * 4096 + kt * 32);
            bfrag af[4];
#pragma unroll
            for (int mi = 0; mi < 4; ++mi)
                af[mi] = *reinterpret_cast<const bfrag*>(&At[mi * 16 + lr][kt * 32 + lh * 8]);
#pragma unroll
            for (int ni = 0; ni < 4; ++ni)
#pragma unroll
                for (int mi = 0; mi < 4; ++mi)
                    acc[mi][ni] = __builtin_amdgcn_mfma_f32_16x16x32_bf16(af[mi], bf[ni], acc[mi][ni], 0, 0, 0);
        }
        if (z == 2) {
            for (int ni = 0; ni < 4; ++ni) {
                const int col = w * 64 + ni * 16 + lr;
                const float bb = bv[col];
                for (int mi = 0; mi < 4; ++mi) {
                    const int pos = (m0 & 1023) + mi * 16 + lh * 4;
                    s16x4 ov;
                    for (int j = 0; j < 4; ++j) ov[j] = f2b(acc[mi][ni][j] + bb);
                    *reinterpret_cast<s16x4*>(&vtg[(((b << 8) + col) << 10) + pos]) = ov;
                }
            }
        } else {
            short* outp = (z == 0) ? qo : ko;
            const float* bias = (z == 0) ? bq : bk;
            const float s = (z == 0) ? QSC : 1.0f;
            for (int ni = 0; ni < 4; ++ni) {
                const int col = w * 64 + ni * 16 + lr;
                const float bsc = bias[col] * s;
                for (int mi = 0; mi < 4; ++mi) {
                    const int row = m0 + mi * 16 + lh * 4;
                    for (int j = 0; j < 4; ++j)
                        outp[(row + j) * 256 + col] = f2b(acc[mi][ni][j] * s + bsc);
                }
            }
        }
    }
}

// ---------------------------------------------------------------------------
// K3: flash attention (proven r5 loop) + FUSED output projection.
// 8 waves (512 thr), QBLK=128, grid 256 (XCD-swizzled) = 1 block/CU.
// Epilogue: oproj accumulator INITIALIZED with x + bias (MFMA C-in), so the
// residual x loads issue before the GEMM and their HBM latency hides under
// the 64-MFMA chain + Ot staging.
// ---------------------------------------------------------------------------
__global__ __launch_bounds__(512) void attn_fused(const short* __restrict__ qq,
                                                  const short* __restrict__ kk,
                                                  const short* __restrict__ vt,
                                                  const short* __restrict__ wto,
                                                  const float* __restrict__ bo,
                                                  const float* __restrict__ x,
                                                  float* __restrict__ out) {
    // LDS pool: Kt[buf]=L+buf*16384 (2x32KB); Vt[buf]=L+32768+buf*16384
    // (2x32KB); Pl[w]=L+65536+w*1024 (8x2KB); epilogue alias Ot[128][264].
    __shared__ __align__(1024) short L[73728];   // 144 KB

    int bid = blockIdx.x;
    bid = ((bid & 7) << 5) | (bid >> 3);   // XCD swizzle: 4 batches/XCD in L2
    const int b = bid >> 3, qt = bid & 7;
    const int t = threadIdx.x;
    const int w = t >> 6, lane = t & 63;
    const int lr = lane & 15, lh = lane >> 4;
    const int qr0 = qt * 128 + w * 16;
    const int sw = lr & 7;

    bfrag qf[8];
    {
        const short* qp = qq + (((b << 10) + qr0 + lr) << 8) + lh * 8;
#pragma unroll
        for (int ks = 0; ks < 8; ++ks)
            qf[ks] = *reinterpret_cast<const bfrag*>(qp + ks * 32);
    }

    const short* kbase = kk + ((long)b << 18);
    const short* vbase = vt + ((long)b << 18);
    short* plw = L + 65536 + (w << 10);

    auto stageK = [&](int kt_, int buf) {
#pragma unroll
        for (int t2 = 0; t2 < 4; ++t2) {
            const int rbase = w * 8 + t2 * 2;
            const int r  = rbase + (lane >> 5);
            const int gs = (lane & 31) ^ (r & 7);
            GLDS16(kbase + ((kt_ * 64 + r) << 8) + (gs << 3),
                   &L[buf * 16384 + (rbase << 8)]);
        }
    };
    auto stageV = [&](int kt_, int buf) {
#pragma unroll
        for (int t2 = 0; t2 < 4; ++t2) {
            const int rbase = w * 32 + t2 * 8;
            const int r  = rbase + (lane >> 3);
            const int gs = (lane & 7) ^ (r & 7);
            GLDS16(vbase + (r << 10) + kt_ * 64 + (gs << 3),
                   &L[32768 + buf * 16384 + (rbase << 6)]);
        }
    };

    f32x4 o[16];
#pragma unroll
    for (int ci = 0; ci < 16; ++ci) o[ci] = (f32x4){0.f, 0.f, 0.f, 0.f};
    float m = -3e38f, lsum = 0.f;

    stageK(0, 0); stageV(0, 0);

    for (int kt = 0; kt < 16; ++kt) {
        const int cur = kt & 1;
        __asm__ volatile("s_barrier" ::: "memory");
        if (kt < 15) {
            stageK(kt + 1, cur ^ 1);
            stageV(kt + 1, cur ^ 1);
            __asm__ volatile("s_waitcnt vmcnt(8)" ::: "memory");
        } else {
            __asm__ volatile("s_waitcnt vmcnt(0)" ::: "memory");
        }
        __asm__ volatile("s_barrier" ::: "memory");

        // ---- S^T = K . Q
        f32x4 sacc[4];
#pragma unroll
        for (int ni = 0; ni < 4; ++ni) sacc[ni] = (f32x4){0.f, 0.f, 0.f, 0.f};
        __builtin_amdgcn_s_setprio(1);
#pragma unroll
        for (int ks = 0; ks < 8; ++ks) {
#pragma unroll
            for (int ni = 0; ni < 4; ++ni) {
                const int row = ni * 16 + lr;
                const bfrag kf = *reinterpret_cast<const bfrag*>(
                    &L[cur * 16384 + (row << 8) + ((((ks << 2) + lh) ^ sw) << 3)]);
                sacc[ni] = __builtin_amdgcn_mfma_f32_16x16x32_bf16(kf, qf[ks], sacc[ni], 0, 0, 0);
            }
        }
        __builtin_amdgcn_s_setprio(0);

        // ---- online softmax, per-lane state for q-row lr
        float rm = fmaxf(fmaxf(sacc[0][0], sacc[0][1]), fmaxf(sacc[0][2], sacc[0][3]));
#pragma unroll
        for (int ni = 1; ni < 4; ++ni)
            rm = fmaxf(rm, fmaxf(fmaxf(sacc[ni][0], sacc[ni][1]),
                                 fmaxf(sacc[ni][2], sacc[ni][3])));
        rm = fmaxf(rm, __shfl_xor(rm, 16));
        rm = fmaxf(rm, __shfl_xor(rm, 32));

        const bool grow = __any(rm > m);
        float p[4][4];
        float rs = 0.f;
        if (grow) {
            const float mn = fmaxf(m, rm);
            const float sc = __expf(m - mn);
            m = mn;
#pragma unroll
            for (int ni = 0; ni < 4; ++ni)
#pragma unroll
                for (int r2 = 0; r2 < 4; ++r2) {
                    p[ni][r2] = __expf(sacc[ni][r2] - mn);
                    rs += p[ni][r2];
                }
            rs += __shfl_xor(rs, 16);
            rs += __shfl_xor(rs, 32);
            lsum = lsum * sc + rs;
            float scb[4];
#pragma unroll
            for (int j = 0; j < 4; ++j) scb[j] = __shfl(sc, lh * 4 + j);
#pragma unroll
            for (int ci = 0; ci < 16; ++ci)
#pragma unroll
                for (int j = 0; j < 4; ++j) o[ci][j] *= scb[j];
        } else {
#pragma unroll
            for (int ni = 0; ni < 4; ++ni)
#pragma unroll
                for (int r2 = 0; r2 < 4; ++r2) {
                    p[ni][r2] = __expf(sacc[ni][r2] - m);
                    rs += p[ni][r2];
                }
            rs += __shfl_xor(rs, 16);
            rs += __shfl_xor(rs, 32);
            lsum += rs;
        }

        // ---- stage P
#pragma unroll
        for (int ni = 0; ni < 4; ++ni) {
            s16x4 pw;
#pragma unroll
            for (int r2 = 0; r2 < 4; ++r2) pw[r2] = f2b(p[ni][r2]);
            const int gc = (ni << 1) + (lh >> 1);
            const int ad = (lr << 6) + ((gc ^ sw) << 3) + ((lh & 1) << 2);
            *reinterpret_cast<s16x4*>(&plw[ad]) = pw;
        }
        const bfrag pa0 = *reinterpret_cast<const bfrag*>(
            &plw[(lr << 6) + ((lh ^ sw) << 3)]);
        const bfrag pa1 = *reinterpret_cast<const bfrag*>(
            &plw[(lr << 6) + (((4 + lh) ^ sw) << 3)]);

        // ---- O += P . V
        __builtin_amdgcn_s_setprio(1);
#pragma unroll
        for (int ci = 0; ci < 16; ++ci) {
            const int row = (ci << 4) + lr;
            const bfrag vb0 = *reinterpret_cast<const bfrag*>(
                &L[32768 + cur * 16384 + (row << 6) + ((lh ^ sw) << 3)]);
            const bfrag vb1 = *reinterpret_cast<const bfrag*>(
                &L[32768 + cur * 16384 + (row << 6) + (((4 + lh) ^ sw) << 3)]);
            o[ci] = __builtin_amdgcn_mfma_f32_16x16x32_bf16(pa0, vb0, o[ci], 0, 0, 0);
            o[ci] = __builtin_amdgcn_mfma_f32_16x16x32_bf16(pa1, vb1, o[ci], 0, 0, 0);
        }
        __builtin_amdgcn_s_setprio(0);
    }

    float invb[4];
#pragma unroll
    for (int j = 0; j < 4; ++j) invb[j] = 1.0f / __shfl(lsum, lh * 4 + j);

    // ================= fused output projection =================
    __syncthreads();   // Kt/Vt/Pl dead -> reuse L as Ot[128][264]

    // acc init = x + bias (C-in): residual loads issue BEFORE the GEMM,
    // latency hides under Ot staging + 64-MFMA chain.
    const int m0r = (b << 10) + qt * 128;
    f32x4 acc[8][2];
#pragma unroll
    for (int ni = 0; ni < 2; ++ni) {
        const int col = w * 32 + ni * 16 + lr;
        const float bb = bo[col];
#pragma unroll
        for (int mi = 0; mi < 8; ++mi)
#pragma unroll
            for (int j = 0; j < 4; ++j)
                acc[mi][ni][j] = x[(m0r + mi * 16 + lh * 4 + j) * 256 + col] + bb;
    }

    // write normalized O (bf16) into Ot; wave w owns local rows w*16..+15
#pragma unroll
    for (int j = 0; j < 4; ++j) {
        const int rloc = w * 16 + lh * 4 + j;
#pragma unroll
        for (int ci = 0; ci < 16; ++ci)
            L[rloc * 264 + (ci << 4) + lr] = f2b(o[ci][j] * invb[j]);
    }
    __syncthreads();

    // per-block GEMM: Ot[128][256] x Wo^T; 8 waves x 32 cols
    const short* wz = wto + (w * 32 + lr) * 256 + lh * 8;
#pragma unroll
    for (int kt = 0; kt < 8; ++kt) {
        bfrag bf[2];
#pragma unroll
        for (int ni = 0; ni < 2; ++ni)
            bf[ni] = *reinterpret_cast<const bfrag*>(wz + ni * 4096 + kt * 32);
        bfrag af[8];
#pragma unroll
        for (int mi = 0; mi < 8; ++mi)
            af[mi] = *reinterpret_cast<const bfrag*>(
                &L[(mi * 16 + lr) * 264 + kt * 32 + lh * 8]);
#pragma unroll
        for (int ni = 0; ni < 2; ++ni)
#pragma unroll
            for (int mi = 0; mi < 8; ++mi)
                acc[mi][ni] = __builtin_amdgcn_mfma_f32_16x16x32_bf16(af[mi], bf[ni], acc[mi][ni], 0, 0, 0);
    }

#pragma unroll
    for (int ni = 0; ni < 2; ++ni) {
        const int col = w * 32 + ni * 16 + lr;
#pragma unroll
        for (int mi = 0; mi < 8; ++mi) {
            const int row = m0r + mi * 16 + lh * 4;
#pragma unroll
            for (int j = 0; j < 4; ++j)
                out[(row + j) * 256 + col] = acc[mi][ni][j];
        }
    }
}

// ---------------------------------------------------------------------------
extern "C" void kernel_launch(void* const* d_in, const int* in_sizes, int n_in,
                              void* d_out, int out_size, void* d_ws, size_t ws_size,
                              hipStream_t stream) {
    const float* x   = (const float*)d_in[0];
    const float* gns = (const float*)d_in[1];
    const float* gnb = (const float*)d_in[2];
    const float* Wq  = (const float*)d_in[3];
    const float* bq  = (const float*)d_in[4];
    const float* Wk  = (const float*)d_in[5];
    const float* bk  = (const float*)d_in[6];
    const float* Wv  = (const float*)d_in[7];
    const float* bv  = (const float*)d_in[8];
    const float* Wo  = (const float*)d_in[9];
    const float* bo  = (const float*)d_in[10];
    float* out = (float*)d_out;

    char* ws = (char*)d_ws;
    short* wt   = (short*)(ws);
    float* part = (float*)(ws + 524288);
    const size_t MB16 = 16777216;
    short* qb  = (short*)(ws + (1 << 20));
    short* kb  = (short*)(ws + (1 << 20) + MB16);
    short* vtb = (short*)(ws + (1 << 20) + 2 * MB16);

    hipLaunchKernelGGL(gn_part_prep, dim3(1280), dim3(256), 0, stream,
                       x, part, Wq, Wk, Wv, Wo, wt);
    hipLaunchKernelGGL(qkv_gemm, dim3(512), dim3(256), 0, stream,
                       x, part, gns, gnb, wt, bq, bk, bv, qb, kb, vtb);
    hipLaunchKernelGGL(attn_fused, dim3(256), dim3(512), 0, stream,
                       qb, kb, vtb, wt + 3 * 65536, bo, x, out);
}

// Round 15
// 115.241 us; speedup vs baseline: 1.9438x; 1.1401x over previous
//
#include <hip/hip_runtime.h>
#include <hip/hip_bf16.h>

#define EPSV  1e-5f
#define QSC   0.0625f     // C^-0.5 (natural-exp softmax)

typedef __attribute__((ext_vector_type(8))) __bf16 bfrag;   // MFMA A/B operand
typedef __attribute__((ext_vector_type(4))) float  f32x4;
typedef __attribute__((ext_vector_type(8))) short  s16x8;
typedef __attribute__((ext_vector_type(4))) short  s16x4;

static __device__ __forceinline__ short f2b(float f) {
    __hip_bfloat16 h = __float2bfloat16(f);
    return __builtin_bit_cast(short, h);
}

// async global->LDS, 16B per lane; LDS dest = wave-uniform base + lane*16
#define GLDS16(SRC, DST) __builtin_amdgcn_global_load_lds( \
    (__attribute__((address_space(1))) void*)(SRC),        \
    (__attribute__((address_space(3))) void*)(DST), 16, 0, 0)

// ---------------------------------------------------------------------------
// K1: GroupNorm partial sums (blocks 0..255)  +  weight transpose to bf16
//     (blocks 256..1279) fused into one launch.
// ---------------------------------------------------------------------------
__global__ __launch_bounds__(256) void gn_part_prep(const float* __restrict__ x,
                                                    float* __restrict__ part,
                                                    const float* __restrict__ wq,
                                                    const float* __restrict__ wk,
                                                    const float* __restrict__ wv,
                                                    const float* __restrict__ wo,
                                                    short* __restrict__ wt) {
    if (blockIdx.x >= 256) {
        const int bb = blockIdx.x - 256;
        const int z = bb >> 8;
        const int n = bb & 255;
        const int k = threadIdx.x;
        const float* w = (z == 0) ? wq : (z == 1) ? wk : (z == 2) ? wv : wo;
        wt[(z * 256 + n) * 256 + k] = f2b(w[k * 256 + n]);
        return;
    }
    const int b = blockIdx.x >> 3, ch = blockIdx.x & 7;
    const int t = threadIdx.x;
    const int c4 = t & 63;
    const int rr = t >> 6;
    float s1 = 0.f, s2 = 0.f;
    for (int i = 0; i < 32; ++i) {
        const int pos = ch * 128 + rr + (i << 2);
        const f32x4 v = *reinterpret_cast<const f32x4*>(x + (((b << 10) + pos) << 8) + (c4 << 2));
        s1 += v[0] + v[1] + v[2] + v[3];
        s2 += v[0]*v[0] + v[1]*v[1] + v[2]*v[2] + v[3]*v[3];
    }
    __shared__ float ls1[256], ls2[256];
    ls1[t] = s1; ls2[t] = s2;
    __syncthreads();
    if (t < 32) {
        float a1 = 0.f, a2 = 0.f;
        for (int r2 = 0; r2 < 4; ++r2)
            for (int e = 0; e < 2; ++e) {
                const int idx = r2 * 64 + t * 2 + e;
                a1 += ls1[idx]; a2 += ls2[idx];
            }
        part[((b * 8 + ch) * 32 + t) * 2 + 0] = a1;
        part[((b * 8 + ch) * 32 + t) * 2 + 1] = a2;
    }
}

// ---------------------------------------------------------------------------
// K2: fused GN-finalize + GN-normalize + QKV projection.
// q/k epilogues staged through LDS -> coalesced s16x8 stores (short store
// queue; next z's B-loads don't wait behind 64 scalar stores).
// ---------------------------------------------------------------------------
__global__ __launch_bounds__(256) void qkv_gemm(const float* __restrict__ x,
                                                const float* __restrict__ part,
                                                const float* __restrict__ gns,
                                                const float* __restrict__ gnb,
                                                const short* __restrict__ wt,
                                                const float* __restrict__ bq,
                                                const float* __restrict__ bk,
                                                const float* __restrict__ bv,
                                                short* __restrict__ qo,
                                                short* __restrict__ ko,
                                                short* __restrict__ vtg) {
    __shared__ short At[64][264];
    __shared__ short Qs[64][264];   // output staging tile (q/k)
    __shared__ float gmean[32], grstd[32];
    __shared__ float sA[256], sB[256];

    const int t  = threadIdx.x;
    const int m0 = blockIdx.x * 64;
    const int b  = m0 >> 10;
    const int lane = t & 63, w = t >> 6;
    const int lr = lane & 15, lh = lane >> 4;

    if (t < 32) {
        float s1 = 0.f, s2 = 0.f;
        for (int ch = 0; ch < 8; ++ch) {
            s1 += part[((b * 8 + ch) * 32 + t) * 2 + 0];
            s2 += part[((b * 8 + ch) * 32 + t) * 2 + 1];
        }
        const float mean = s1 * (1.f / 8192.f);
        const float var  = s2 * (1.f / 8192.f) - mean * mean;
        gmean[t] = mean;
        grstd[t] = rsqrtf(var + EPSV);
    }
    __syncthreads();
    {
        const float a = grstd[t >> 3] * gns[t];
        sA[t] = a;
        sB[t] = gnb[t] - gmean[t >> 3] * a;
    }
    __syncthreads();

    {
        const int r = t >> 2, q4 = t & 3;
        const float* xrow = x + (m0 + r) * 256;
        for (int i = 0; i < 16; ++i) {
            const int c0 = (q4 + 4 * i) * 4;
            const f32x4 v  = *reinterpret_cast<const f32x4*>(xrow + c0);
            const f32x4 aa = *reinterpret_cast<const f32x4*>(&sA[c0]);
            const f32x4 bb = *reinterpret_cast<const f32x4*>(&sB[c0]);
            s16x4 o;
            for (int j = 0; j < 4; ++j) o[j] = f2b(v[j] * aa[j] + bb[j]);
            *reinterpret_cast<s16x4*>(&At[r][c0]) = o;
        }
    }
    __syncthreads();

    for (int z = 0; z < 3; ++z) {
        f32x4 acc[4][4];
        for (int mi = 0; mi < 4; ++mi)
            for (int ni = 0; ni < 4; ++ni) acc[mi][ni] = (f32x4){0.f, 0.f, 0.f, 0.f};
        const short* wz = wt + z * 65536 + (w * 64 + lr) * 256 + lh * 8;
#pragma unroll
        for (int kt = 0; kt < 8; ++kt) {
            bfrag bf[4];
#pragma unroll
            for (int ni = 0; ni < 4; ++ni)
                bf[ni] = *reinterpret_cast<const bfrag*>(wz + ni * 4096 + kt * 32);
            bfrag af[4];
#pragma unroll
            for (int mi = 0; mi < 4; ++mi)
                af[mi] = *reinterpret_cast<const bfrag*>(&At[mi * 16 + lr][kt * 32 + lh * 8]);
#pragma unroll
            for (int ni = 0; ni < 4; ++ni)
#pragma unroll
                for (int mi = 0; mi < 4; ++mi)
                    acc[mi][ni] = __builtin_amdgcn_mfma_f32_16x16x32_bf16(af[mi], bf[ni], acc[mi][ni], 0, 0, 0);
        }
        if (z == 2) {
            // V: transposed vectorized store, direct
            for (int ni = 0; ni < 4; ++ni) {
                const int col = w * 64 + ni * 16 + lr;
                const float bb = bv[col];
                for (int mi = 0; mi < 4; ++mi) {
                    const int pos = (m0 & 1023) + mi * 16 + lh * 4;
                    s16x4 ov;
                    for (int j = 0; j < 4; ++j) ov[j] = f2b(acc[mi][ni][j] + bb);
                    *reinterpret_cast<s16x4*>(&vtg[(((b << 8) + col) << 10) + pos]) = ov;
                }
            }
        } else {
            // q/k: stage into Qs, then coalesced s16x8 stores
            if (z == 1) __syncthreads();   // z=0 store-phase readers done
            short* outp = (z == 0) ? qo : ko;
            const float* bias = (z == 0) ? bq : bk;
            const float s = (z == 0) ? QSC : 1.0f;
            for (int ni = 0; ni < 4; ++ni) {
                const int col = w * 64 + ni * 16 + lr;
                const float bsc = bias[col] * s;
                for (int mi = 0; mi < 4; ++mi)
                    for (int j = 0; j < 4; ++j)
                        Qs[mi * 16 + lh * 4 + j][col] = f2b(acc[mi][ni][j] * s + bsc);
            }
            __syncthreads();
            {
                const int r = t >> 2, q4 = t & 3;
                short* dst = outp + (m0 + r) * 256;
                const short* src = &Qs[r][0];
#pragma unroll
                for (int i = 0; i < 8; ++i) {
                    const int c0 = (q4 + 4 * i) * 8;
                    *reinterpret_cast<s16x8*>(dst + c0) =
                        *reinterpret_cast<const s16x8*>(src + c0);
                }
            }
        }
    }
}

// ---------------------------------------------------------------------------
// K3: flash attention (proven r5 loop) + FUSED output projection.
// Epilogue: GEMM acc (bias C-init) -> f32 LDS tile [128][264] -> fully
// coalesced float4 {LDS read + x load + add + out store} phase.
// ---------------------------------------------------------------------------
__global__ __launch_bounds__(512) void attn_fused(const short* __restrict__ qq,
                                                  const short* __restrict__ kk,
                                                  const short* __restrict__ vt,
                                                  const short* __restrict__ wto,
                                                  const float* __restrict__ bo,
                                                  const float* __restrict__ x,
                                                  float* __restrict__ out) {
    // LDS pool: Kt[buf]=L+buf*16384 (2x32KB); Vt[buf]=L+32768+buf*16384
    // (2x32KB); Pl[w]=L+65536+w*1024 (8x2KB).
    // Epilogue aliases: Ot[128][264] bf16, then Lf[128][264] f32 (135KB).
    __shared__ __align__(1024) short L[73728];   // 144 KB

    int bid = blockIdx.x;
    bid = ((bid & 7) << 5) | (bid >> 3);   // XCD swizzle: 4 batches/XCD in L2
    const int b = bid >> 3, qt = bid & 7;
    const int t = threadIdx.x;
    const int w = t >> 6, lane = t & 63;
    const int lr = lane & 15, lh = lane >> 4;
    const int qr0 = qt * 128 + w * 16;
    const int sw = lr & 7;

    bfrag qf[8];
    {
        const short* qp = qq + (((b << 10) + qr0 + lr) << 8) + lh * 8;
#pragma unroll
        for (int ks = 0; ks < 8; ++ks)
            qf[ks] = *reinterpret_cast<const bfrag*>(qp + ks * 32);
    }

    const short* kbase = kk + ((long)b << 18);
    const short* vbase = vt + ((long)b << 18);
    short* plw = L + 65536 + (w << 10);

    auto stageK = [&](int kt_, int buf) {
#pragma unroll
        for (int t2 = 0; t2 < 4; ++t2) {
            const int rbase = w * 8 + t2 * 2;
            const int r  = rbase + (lane >> 5);
            const int gs = (lane & 31) ^ (r & 7);
            GLDS16(kbase + ((kt_ * 64 + r) << 8) + (gs << 3),
                   &L[buf * 16384 + (rbase << 8)]);
        }
    };
    auto stageV = [&](int kt_, int buf) {
#pragma unroll
        for (int t2 = 0; t2 < 4; ++t2) {
            const int rbase = w * 32 + t2 * 8;
            const int r  = rbase + (lane >> 3);
            const int gs = (lane & 7) ^ (r & 7);
            GLDS16(vbase + (r << 10) + kt_ * 64 + (gs << 3),
                   &L[32768 + buf * 16384 + (rbase << 6)]);
        }
    };

    f32x4 o[16];
#pragma unroll
    for (int ci = 0; ci < 16; ++ci) o[ci] = (f32x4){0.f, 0.f, 0.f, 0.f};
    float m = -3e38f, lsum = 0.f;

    stageK(0, 0); stageV(0, 0);

    for (int kt = 0; kt < 16; ++kt) {
        const int cur = kt & 1;
        __asm__ volatile("s_barrier" ::: "memory");
        if (kt < 15) {
            stageK(kt + 1, cur ^ 1);
            stageV(kt + 1, cur ^ 1);
            __asm__ volatile("s_waitcnt vmcnt(8)" ::: "memory");
        } else {
            __asm__ volatile("s_waitcnt vmcnt(0)" ::: "memory");
        }
        __asm__ volatile("s_barrier" ::: "memory");

        // ---- S^T = K . Q
        f32x4 sacc[4];
#pragma unroll
        for (int ni = 0; ni < 4; ++ni) sacc[ni] = (f32x4){0.f, 0.f, 0.f, 0.f};
        __builtin_amdgcn_s_setprio(1);
#pragma unroll
        for (int ks = 0; ks < 8; ++ks) {
#pragma unroll
            for (int ni = 0; ni < 4; ++ni) {
                const int row = ni * 16 + lr;
                const bfrag kf = *reinterpret_cast<const bfrag*>(
                    &L[cur * 16384 + (row << 8) + ((((ks << 2) + lh) ^ sw) << 3)]);
                sacc[ni] = __builtin_amdgcn_mfma_f32_16x16x32_bf16(kf, qf[ks], sacc[ni], 0, 0, 0);
            }
        }
        __builtin_amdgcn_s_setprio(0);

        // ---- online softmax, per-lane state for q-row lr
        float rm = fmaxf(fmaxf(sacc[0][0], sacc[0][1]), fmaxf(sacc[0][2], sacc[0][3]));
#pragma unroll
        for (int ni = 1; ni < 4; ++ni)
            rm = fmaxf(rm, fmaxf(fmaxf(sacc[ni][0], sacc[ni][1]),
                                 fmaxf(sacc[ni][2], sacc[ni][3])));
        rm = fmaxf(rm, __shfl_xor(rm, 16));
        rm = fmaxf(rm, __shfl_xor(rm, 32));

        const bool grow = __any(rm > m);
        float p[4][4];
        float rs = 0.f;
        if (grow) {
            const float mn = fmaxf(m, rm);
            const float sc = __expf(m - mn);
            m = mn;
#pragma unroll
            for (int ni = 0; ni < 4; ++ni)
#pragma unroll
                for (int r2 = 0; r2 < 4; ++r2) {
                    p[ni][r2] = __expf(sacc[ni][r2] - mn);
                    rs += p[ni][r2];
                }
            rs += __shfl_xor(rs, 16);
            rs += __shfl_xor(rs, 32);
            lsum = lsum * sc + rs;
            float scb[4];
#pragma unroll
            for (int j = 0; j < 4; ++j) scb[j] = __shfl(sc, lh * 4 + j);
#pragma unroll
            for (int ci = 0; ci < 16; ++ci)
#pragma unroll
                for (int j = 0; j < 4; ++j) o[ci][j] *= scb[j];
        } else {
#pragma unroll
            for (int ni = 0; ni < 4; ++ni)
#pragma unroll
                for (int r2 = 0; r2 < 4; ++r2) {
                    p[ni][r2] = __expf(sacc[ni][r2] - m);
                    rs += p[ni][r2];
                }
            rs += __shfl_xor(rs, 16);
            rs += __shfl_xor(rs, 32);
            lsum += rs;
        }

        // ---- stage P
#pragma unroll
        for (int ni = 0; ni < 4; ++ni) {
            s16x4 pw;
#pragma unroll
            for (int r2 = 0; r2 < 4; ++r2) pw[r2] = f2b(p[ni][r2]);
            const int gc = (ni << 1) + (lh >> 1);
            const int ad = (lr << 6) + ((gc ^ sw) << 3) + ((lh & 1) << 2);
            *reinterpret_cast<s16x4*>(&plw[ad]) = pw;
        }
        const bfrag pa0 = *reinterpret_cast<const bfrag*>(
            &plw[(lr << 6) + ((lh ^ sw) << 3)]);
        const bfrag pa1 = *reinterpret_cast<const bfrag*>(
            &plw[(lr << 6) + (((4 + lh) ^ sw) << 3)]);

        // ---- O += P . V
        __builtin_amdgcn_s_setprio(1);
#pragma unroll
        for (int ci = 0; ci < 16; ++ci) {
            const int row = (ci << 4) + lr;
            const bfrag vb0 = *reinterpret_cast<const bfrag*>(
                &L[32768 + cur * 16384 + (row << 6) + ((lh ^ sw) << 3)]);
            const bfrag vb1 = *reinterpret_cast<const bfrag*>(
                &L[32768 + cur * 16384 + (row << 6) + (((4 + lh) ^ sw) << 3)]);
            o[ci] = __builtin_amdgcn_mfma_f32_16x16x32_bf16(pa0, vb0, o[ci], 0, 0, 0);
            o[ci] = __builtin_amdgcn_mfma_f32_16x16x32_bf16(pa1, vb1, o[ci], 0, 0, 0);
        }
        __builtin_amdgcn_s_setprio(0);
    }

    float invb[4];
#pragma unroll
    for (int j = 0; j < 4; ++j) invb[j] = 1.0f / __shfl(lsum, lh * 4 + j);

    // ================= fused output projection =================
    __syncthreads();   // Kt/Vt/Pl dead -> reuse L as Ot[128][264] (bf16)

    // write normalized O (bf16) into Ot; wave w owns local rows w*16..+15
#pragma unroll
    for (int j = 0; j < 4; ++j) {
        const int rloc = w * 16 + lh * 4 + j;
#pragma unroll
        for (int ci = 0; ci < 16; ++ci)
            L[rloc * 264 + (ci << 4) + lr] = f2b(o[ci][j] * invb[j]);
    }
    __syncthreads();

    // per-block GEMM: Ot[128][256] x Wo^T; 8 waves x 32 cols; C-init = bias
    const int m0r = (b << 10) + qt * 128;
    f32x4 acc[8][2];
#pragma unroll
    for (int ni = 0; ni < 2; ++ni) {
        const float bb = bo[w * 32 + ni * 16 + lr];
#pragma unroll
        for (int mi = 0; mi < 8; ++mi)
            acc[mi][ni] = (f32x4){bb, bb, bb, bb};
    }
    const short* wz = wto + (w * 32 + lr) * 256 + lh * 8;
#pragma unroll
    for (int kt = 0; kt < 8; ++kt) {
        bfrag bf[2];
#pragma unroll
        for (int ni = 0; ni < 2; ++ni)
            bf[ni] = *reinterpret_cast<const bfrag*>(wz + ni * 4096 + kt * 32);
        bfrag af[8];
#pragma unroll
        for (int mi = 0; mi < 8; ++mi)
            af[mi] = *reinterpret_cast<const bfrag*>(
                &L[(mi * 16 + lr) * 264 + kt * 32 + lh * 8]);
#pragma unroll
        for (int ni = 0; ni < 2; ++ni)
#pragma unroll
            for (int mi = 0; mi < 8; ++mi)
                acc[mi][ni] = __builtin_amdgcn_mfma_f32_16x16x32_bf16(af[mi], bf[ni], acc[mi][ni], 0, 0, 0);
    }

    __syncthreads();   // all Ot reads done -> reuse L as Lf[128][264] f32
    float* Lf = reinterpret_cast<float*>(L);
#pragma unroll
    for (int ni = 0; ni < 2; ++ni) {
        const int col = w * 32 + ni * 16 + lr;
#pragma unroll
        for (int mi = 0; mi < 8; ++mi)
#pragma unroll
            for (int j = 0; j < 4; ++j)
                Lf[(mi * 16 + lh * 4 + j) * 264 + col] = acc[mi][ni][j];
    }
    __syncthreads();

    // fully-coalesced out = Lf + x : thread t owns row t>>2, quarter t&3
    {
        const int r = t >> 2, q4 = t & 3;
        const float* xrow = x + (m0r + r) * 256;
        float* orow = out + (m0r + r) * 256;
        const float* lrow = Lf + r * 264;
#pragma unroll
        for (int i = 0; i < 16; ++i) {
            const int c0 = (q4 + 4 * i) * 4;
            const f32x4 lv = *reinterpret_cast<const f32x4*>(lrow + c0);
            const f32x4 xv = *reinterpret_cast<const f32x4*>(xrow + c0);
            f32x4 ov;
#pragma unroll
            for (int j = 0; j < 4; ++j) ov[j] = lv[j] + xv[j];
            *reinterpret_cast<f32x4*>(orow + c0) = ov;
        }
    }
}

// ---------------------------------------------------------------------------
extern "C" void kernel_launch(void* const* d_in, const int* in_sizes, int n_in,
                              void* d_out, int out_size, void* d_ws, size_t ws_size,
                              hipStream_t stream) {
    const float* x   = (const float*)d_in[0];
    const float* gns = (const float*)d_in[1];
    const float* gnb = (const float*)d_in[2];
    const float* Wq  = (const float*)d_in[3];
    const float* bq  = (const float*)d_in[4];
    const float* Wk  = (const float*)d_in[5];
    const float* bk  = (const float*)d_in[6];
    const float* Wv  = (const float*)d_in[7];
    const float* bv  = (const float*)d_in[8];
    const float* Wo  = (const float*)d_in[9];
    const float* bo  = (const float*)d_in[10];
    float* out = (float*)d_out;

    char* ws = (char*)d_ws;
    short* wt   = (short*)(ws);
    float* part = (float*)(ws + 524288);
    const size_t MB16 = 16777216;
    short* qb  = (short*)(ws + (1 << 20));
    short* kb  = (short*)(ws + (1 << 20) + MB16);
    short* vtb = (short*)(ws + (1 << 20) + 2 * MB16);

    hipLaunchKernelGGL(gn_part_prep, dim3(1280), dim3(256), 0, stream,
                       x, part, Wq, Wk, Wv, Wo, wt);
    hipLaunchKernelGGL(qkv_gemm, dim3(512), dim3(256), 0, stream,
                       x, part, gns, gnb, wt, bq, bk, bv, qb, kb, vtb);
    hipLaunchKernelGGL(attn_fused, dim3(256), dim3(512), 0, stream,
                       qb, kb, vtb, wt + 3 * 65536, bo, x, out);
}

// Round 16
// 114.608 us; speedup vs baseline: 1.9546x; 1.0055x over previous
//
#include <hip/hip_runtime.h>
#include <hip/hip_bf16.h>

#define EPSV  1e-5f
#define QSC   0.0625f     // C^-0.5 (natural-exp softmax)
#define DTHR  8.0f        // defer-max rescale threshold (natural-log units)

typedef __attribute__((ext_vector_type(8))) __bf16 bfrag;   // MFMA A/B operand
typedef __attribute__((ext_vector_type(4))) float  f32x4;
typedef __attribute__((ext_vector_type(8))) short  s16x8;
typedef __attribute__((ext_vector_type(4))) short  s16x4;

static __device__ __forceinline__ short f2b(float f) {
    __hip_bfloat16 h = __float2bfloat16(f);
    return __builtin_bit_cast(short, h);
}

// async global->LDS, 16B per lane; LDS dest = wave-uniform base + lane*16
#define GLDS16(SRC, DST) __builtin_amdgcn_global_load_lds( \
    (__attribute__((address_space(1))) void*)(SRC),        \
    (__attribute__((address_space(3))) void*)(DST), 16, 0, 0)

// ---------------------------------------------------------------------------
// K1: GroupNorm partial sums (blocks 0..255)  +  weight transpose to bf16
//     (blocks 256..1279) fused into one launch.
// ---------------------------------------------------------------------------
__global__ __launch_bounds__(256) void gn_part_prep(const float* __restrict__ x,
                                                    float* __restrict__ part,
                                                    const float* __restrict__ wq,
                                                    const float* __restrict__ wk,
                                                    const float* __restrict__ wv,
                                                    const float* __restrict__ wo,
                                                    short* __restrict__ wt) {
    if (blockIdx.x >= 256) {
        const int bb = blockIdx.x - 256;
        const int z = bb >> 8;
        const int n = bb & 255;
        const int k = threadIdx.x;
        const float* w = (z == 0) ? wq : (z == 1) ? wk : (z == 2) ? wv : wo;
        wt[(z * 256 + n) * 256 + k] = f2b(w[k * 256 + n]);
        return;
    }
    const int b = blockIdx.x >> 3, ch = blockIdx.x & 7;
    const int t = threadIdx.x;
    const int c4 = t & 63;
    const int rr = t >> 6;
    float s1 = 0.f, s2 = 0.f;
    for (int i = 0; i < 32; ++i) {
        const int pos = ch * 128 + rr + (i << 2);
        const f32x4 v = *reinterpret_cast<const f32x4*>(x + (((b << 10) + pos) << 8) + (c4 << 2));
        s1 += v[0] + v[1] + v[2] + v[3];
        s2 += v[0]*v[0] + v[1]*v[1] + v[2]*v[2] + v[3]*v[3];
    }
    __shared__ float ls1[256], ls2[256];
    ls1[t] = s1; ls2[t] = s2;
    __syncthreads();
    if (t < 32) {
        float a1 = 0.f, a2 = 0.f;
        for (int r2 = 0; r2 < 4; ++r2)
            for (int e = 0; e < 2; ++e) {
                const int idx = r2 * 64 + t * 2 + e;
                a1 += ls1[idx]; a2 += ls2[idx];
            }
        part[((b * 8 + ch) * 32 + t) * 2 + 0] = a1;
        part[((b * 8 + ch) * 32 + t) * 2 + 1] = a2;
    }
}

// ---------------------------------------------------------------------------
// K2: fused GN-finalize + GN-normalize + QKV projection.
// q/k epilogues staged through LDS -> coalesced s16x8 stores.
// ---------------------------------------------------------------------------
__global__ __launch_bounds__(256) void qkv_gemm(const float* __restrict__ x,
                                                const float* __restrict__ part,
                                                const float* __restrict__ gns,
                                                const float* __restrict__ gnb,
                                                const short* __restrict__ wt,
                                                const float* __restrict__ bq,
                                                const float* __restrict__ bk,
                                                const float* __restrict__ bv,
                                                short* __restrict__ qo,
                                                short* __restrict__ ko,
                                                short* __restrict__ vtg) {
    __shared__ short At[64][264];
    __shared__ short Qs[64][264];   // output staging tile (q/k)
    __shared__ float gmean[32], grstd[32];
    __shared__ float sA[256], sB[256];

    const int t  = threadIdx.x;
    const int m0 = blockIdx.x * 64;
    const int b  = m0 >> 10;
    const int lane = t & 63, w = t >> 6;
    const int lr = lane & 15, lh = lane >> 4;

    if (t < 32) {
        float s1 = 0.f, s2 = 0.f;
        for (int ch = 0; ch < 8; ++ch) {
            s1 += part[((b * 8 + ch) * 32 + t) * 2 + 0];
            s2 += part[((b * 8 + ch) * 32 + t) * 2 + 1];
        }
        const float mean = s1 * (1.f / 8192.f);
        const float var  = s2 * (1.f / 8192.f) - mean * mean;
        gmean[t] = mean;
        grstd[t] = rsqrtf(var + EPSV);
    }
    __syncthreads();
    {
        const float a = grstd[t >> 3] * gns[t];
        sA[t] = a;
        sB[t] = gnb[t] - gmean[t >> 3] * a;
    }
    __syncthreads();

    {
        const int r = t >> 2, q4 = t & 3;
        const float* xrow = x + (m0 + r) * 256;
        for (int i = 0; i < 16; ++i) {
            const int c0 = (q4 + 4 * i) * 4;
            const f32x4 v  = *reinterpret_cast<const f32x4*>(xrow + c0);
            const f32x4 aa = *reinterpret_cast<const f32x4*>(&sA[c0]);
            const f32x4 bb = *reinterpret_cast<const f32x4*>(&sB[c0]);
            s16x4 o;
            for (int j = 0; j < 4; ++j) o[j] = f2b(v[j] * aa[j] + bb[j]);
            *reinterpret_cast<s16x4*>(&At[r][c0]) = o;
        }
    }
    __syncthreads();

    for (int z = 0; z < 3; ++z) {
        f32x4 acc[4][4];
        for (int mi = 0; mi < 4; ++mi)
            for (int ni = 0; ni < 4; ++ni) acc[mi][ni] = (f32x4){0.f, 0.f, 0.f, 0.f};
        const short* wz = wt + z * 65536 + (w * 64 + lr) * 256 + lh * 8;
#pragma unroll
        for (int kt = 0; kt < 8; ++kt) {
            bfrag bf[4];
#pragma unroll
            for (int ni = 0; ni < 4; ++ni)
                bf[ni] = *reinterpret_cast<const bfrag*>(wz + ni * 4096 + kt * 32);
            bfrag af[4];
#pragma unroll
            for (int mi = 0; mi < 4; ++mi)
                af[mi] = *reinterpret_cast<const bfrag*>(&At[mi * 16 + lr][kt * 32 + lh * 8]);
#pragma unroll
            for (int ni = 0; ni < 4; ++ni)
#pragma unroll
                for (int mi = 0; mi < 4; ++mi)
                    acc[mi][ni] = __builtin_amdgcn_mfma_f32_16x16x32_bf16(af[mi], bf[ni], acc[mi][ni], 0, 0, 0);
        }
        if (z == 2) {
            // V: transposed vectorized store, direct
            for (int ni = 0; ni < 4; ++ni) {
                const int col = w * 64 + ni * 16 + lr;
                const float bb = bv[col];
                for (int mi = 0; mi < 4; ++mi) {
                    const int pos = (m0 & 1023) + mi * 16 + lh * 4;
                    s16x4 ov;
                    for (int j = 0; j < 4; ++j) ov[j] = f2b(acc[mi][ni][j] + bb);
                    *reinterpret_cast<s16x4*>(&vtg[(((b << 8) + col) << 10) + pos]) = ov;
                }
            }
        } else {
            // q/k: stage into Qs, then coalesced s16x8 stores
            if (z == 1) __syncthreads();   // z=0 store-phase readers done
            short* outp = (z == 0) ? qo : ko;
            const float* bias = (z == 0) ? bq : bk;
            const float s = (z == 0) ? QSC : 1.0f;
            for (int ni = 0; ni < 4; ++ni) {
                const int col = w * 64 + ni * 16 + lr;
                const float bsc = bias[col] * s;
                for (int mi = 0; mi < 4; ++mi)
                    for (int j = 0; j < 4; ++j)
                        Qs[mi * 16 + lh * 4 + j][col] = f2b(acc[mi][ni][j] * s + bsc);
            }
            __syncthreads();
            {
                const int r = t >> 2, q4 = t & 3;
                short* dst = outp + (m0 + r) * 256;
                const short* src = &Qs[r][0];
#pragma unroll
                for (int i = 0; i < 8; ++i) {
                    const int c0 = (q4 + 4 * i) * 8;
                    *reinterpret_cast<s16x8*>(dst + c0) =
                        *reinterpret_cast<const s16x8*>(src + c0);
                }
            }
        }
    }
}

// ---------------------------------------------------------------------------
// K3: flash attention (proven r5 loop + defer-max THR=8) + FUSED oproj.
// Defer-max: skip the O-rescale while the tile max grows by <= DTHR above
// the running max (P bounded by e^8, bf16/f32-safe); exact normalization by
// 1/lsum at the end.  Only the grow condition changed vs round-15.
// ---------------------------------------------------------------------------
__global__ __launch_bounds__(512) void attn_fused(const short* __restrict__ qq,
                                                  const short* __restrict__ kk,
                                                  const short* __restrict__ vt,
                                                  const short* __restrict__ wto,
                                                  const float* __restrict__ bo,
                                                  const float* __restrict__ x,
                                                  float* __restrict__ out) {
    // LDS pool: Kt[buf]=L+buf*16384 (2x32KB); Vt[buf]=L+32768+buf*16384
    // (2x32KB); Pl[w]=L+65536+w*1024 (8x2KB).
    // Epilogue aliases: Ot[128][264] bf16, then Lf[128][264] f32.
    __shared__ __align__(1024) short L[73728];   // 144 KB

    int bid = blockIdx.x;
    bid = ((bid & 7) << 5) | (bid >> 3);   // XCD swizzle: 4 batches/XCD in L2
    const int b = bid >> 3, qt = bid & 7;
    const int t = threadIdx.x;
    const int w = t >> 6, lane = t & 63;
    const int lr = lane & 15, lh = lane >> 4;
    const int qr0 = qt * 128 + w * 16;
    const int sw = lr & 7;

    bfrag qf[8];
    {
        const short* qp = qq + (((b << 10) + qr0 + lr) << 8) + lh * 8;
#pragma unroll
        for (int ks = 0; ks < 8; ++ks)
            qf[ks] = *reinterpret_cast<const bfrag*>(qp + ks * 32);
    }

    const short* kbase = kk + ((long)b << 18);
    const short* vbase = vt + ((long)b << 18);
    short* plw = L + 65536 + (w << 10);

    auto stageK = [&](int kt_, int buf) {
#pragma unroll
        for (int t2 = 0; t2 < 4; ++t2) {
            const int rbase = w * 8 + t2 * 2;
            const int r  = rbase + (lane >> 5);
            const int gs = (lane & 31) ^ (r & 7);
            GLDS16(kbase + ((kt_ * 64 + r) << 8) + (gs << 3),
                   &L[buf * 16384 + (rbase << 8)]);
        }
    };
    auto stageV = [&](int kt_, int buf) {
#pragma unroll
        for (int t2 = 0; t2 < 4; ++t2) {
            const int rbase = w * 32 + t2 * 8;
            const int r  = rbase + (lane >> 3);
            const int gs = (lane & 7) ^ (r & 7);
            GLDS16(vbase + (r << 10) + kt_ * 64 + (gs << 3),
                   &L[32768 + buf * 16384 + (rbase << 6)]);
        }
    };

    f32x4 o[16];
#pragma unroll
    for (int ci = 0; ci < 16; ++ci) o[ci] = (f32x4){0.f, 0.f, 0.f, 0.f};
    float m = -3e38f, lsum = 0.f;

    stageK(0, 0); stageV(0, 0);

    for (int kt = 0; kt < 16; ++kt) {
        const int cur = kt & 1;
        __asm__ volatile("s_barrier" ::: "memory");
        if (kt < 15) {
            stageK(kt + 1, cur ^ 1);
            stageV(kt + 1, cur ^ 1);
            __asm__ volatile("s_waitcnt vmcnt(8)" ::: "memory");
        } else {
            __asm__ volatile("s_waitcnt vmcnt(0)" ::: "memory");
        }
        __asm__ volatile("s_barrier" ::: "memory");

        // ---- S^T = K . Q
        f32x4 sacc[4];
#pragma unroll
        for (int ni = 0; ni < 4; ++ni) sacc[ni] = (f32x4){0.f, 0.f, 0.f, 0.f};
        __builtin_amdgcn_s_setprio(1);
#pragma unroll
        for (int ks = 0; ks < 8; ++ks) {
#pragma unroll
            for (int ni = 0; ni < 4; ++ni) {
                const int row = ni * 16 + lr;
                const bfrag kf = *reinterpret_cast<const bfrag*>(
                    &L[cur * 16384 + (row << 8) + ((((ks << 2) + lh) ^ sw) << 3)]);
                sacc[ni] = __builtin_amdgcn_mfma_f32_16x16x32_bf16(kf, qf[ks], sacc[ni], 0, 0, 0);
            }
        }
        __builtin_amdgcn_s_setprio(0);

        // ---- online softmax with defer-max (per-lane q-row = lr)
        float rm = fmaxf(fmaxf(sacc[0][0], sacc[0][1]), fmaxf(sacc[0][2], sacc[0][3]));
#pragma unroll
        for (int ni = 1; ni < 4; ++ni)
            rm = fmaxf(rm, fmaxf(fmaxf(sacc[ni][0], sacc[ni][1]),
                                 fmaxf(sacc[ni][2], sacc[ni][3])));
        rm = fmaxf(rm, __shfl_xor(rm, 16));
        rm = fmaxf(rm, __shfl_xor(rm, 32));

        const bool grow = __any(rm > m + DTHR);   // defer small max growth
        float p[4][4];
        float rs = 0.f;
        if (grow) {
            const float mn = fmaxf(m, rm);
            const float sc = __expf(m - mn);
            m = mn;
#pragma unroll
            for (int ni = 0; ni < 4; ++ni)
#pragma unroll
                for (int r2 = 0; r2 < 4; ++r2) {
                    p[ni][r2] = __expf(sacc[ni][r2] - mn);
                    rs += p[ni][r2];
                }
            rs += __shfl_xor(rs, 16);
            rs += __shfl_xor(rs, 32);
            lsum = lsum * sc + rs;
            float scb[4];
#pragma unroll
            for (int j = 0; j < 4; ++j) scb[j] = __shfl(sc, lh * 4 + j);
#pragma unroll
            for (int ci = 0; ci < 16; ++ci)
#pragma unroll
                for (int j = 0; j < 4; ++j) o[ci][j] *= scb[j];
        } else {
#pragma unroll
            for (int ni = 0; ni < 4; ++ni)
#pragma unroll
                for (int r2 = 0; r2 < 4; ++r2) {
                    p[ni][r2] = __expf(sacc[ni][r2] - m);   // bounded by e^DTHR
                    rs += p[ni][r2];
                }
            rs += __shfl_xor(rs, 16);
            rs += __shfl_xor(rs, 32);
            lsum += rs;
        }

        // ---- stage P
#pragma unroll
        for (int ni = 0; ni < 4; ++ni) {
            s16x4 pw;
#pragma unroll
            for (int r2 = 0; r2 < 4; ++r2) pw[r2] = f2b(p[ni][r2]);
            const int gc = (ni << 1) + (lh >> 1);
            const int ad = (lr << 6) + ((gc ^ sw) << 3) + ((lh & 1) << 2);
            *reinterpret_cast<s16x4*>(&plw[ad]) = pw;
        }
        const bfrag pa0 = *reinterpret_cast<const bfrag*>(
            &plw[(lr << 6) + ((lh ^ sw) << 3)]);
        const bfrag pa1 = *reinterpret_cast<const bfrag*>(
            &plw[(lr << 6) + (((4 + lh) ^ sw) << 3)]);

        // ---- O += P . V
        __builtin_amdgcn_s_setprio(1);
#pragma unroll
        for (int ci = 0; ci < 16; ++ci) {
            const int row = (ci << 4) + lr;
            const bfrag vb0 = *reinterpret_cast<const bfrag*>(
                &L[32768 + cur * 16384 + (row << 6) + ((lh ^ sw) << 3)]);
            const bfrag vb1 = *reinterpret_cast<const bfrag*>(
                &L[32768 + cur * 16384 + (row << 6) + (((4 + lh) ^ sw) << 3)]);
            o[ci] = __builtin_amdgcn_mfma_f32_16x16x32_bf16(pa0, vb0, o[ci], 0, 0, 0);
            o[ci] = __builtin_amdgcn_mfma_f32_16x16x32_bf16(pa1, vb1, o[ci], 0, 0, 0);
        }
        __builtin_amdgcn_s_setprio(0);
    }

    float invb[4];
#pragma unroll
    for (int j = 0; j < 4; ++j) invb[j] = 1.0f / __shfl(lsum, lh * 4 + j);

    // ================= fused output projection =================
    __syncthreads();   // Kt/Vt/Pl dead -> reuse L as Ot[128][264] (bf16)

    // write normalized O (bf16) into Ot; wave w owns local rows w*16..+15
#pragma unroll
    for (int j = 0; j < 4; ++j) {
        const int rloc = w * 16 + lh * 4 + j;
#pragma unroll
        for (int ci = 0; ci < 16; ++ci)
            L[rloc * 264 + (ci << 4) + lr] = f2b(o[ci][j] * invb[j]);
    }
    __syncthreads();

    // per-block GEMM: Ot[128][256] x Wo^T; 8 waves x 32 cols; C-init = bias
    const int m0r = (b << 10) + qt * 128;
    f32x4 acc[8][2];
#pragma unroll
    for (int ni = 0; ni < 2; ++ni) {
        const float bb = bo[w * 32 + ni * 16 + lr];
#pragma unroll
        for (int mi = 0; mi < 8; ++mi)
            acc[mi][ni] = (f32x4){bb, bb, bb, bb};
    }
    const short* wz = wto + (w * 32 + lr) * 256 + lh * 8;
#pragma unroll
    for (int kt = 0; kt < 8; ++kt) {
        bfrag bf[2];
#pragma unroll
        for (int ni = 0; ni < 2; ++ni)
            bf[ni] = *reinterpret_cast<const bfrag*>(wz + ni * 4096 + kt * 32);
        bfrag af[8];
#pragma unroll
        for (int mi = 0; mi < 8; ++mi)
            af[mi] = *reinterpret_cast<const bfrag*>(
                &L[(mi * 16 + lr) * 264 + kt * 32 + lh * 8]);
#pragma unroll
        for (int ni = 0; ni < 2; ++ni)
#pragma unroll
            for (int mi = 0; mi < 8; ++mi)
                acc[mi][ni] = __builtin_amdgcn_mfma_f32_16x16x32_bf16(af[mi], bf[ni], acc[mi][ni], 0, 0, 0);
    }

    __syncthreads();   // all Ot reads done -> reuse L as Lf[128][264] f32
    float* Lf = reinterpret_cast<float*>(L);
#pragma unroll
    for (int ni = 0; ni < 2; ++ni) {
        const int col = w * 32 + ni * 16 + lr;
#pragma unroll
        for (int mi = 0; mi < 8; ++mi)
#pragma unroll
            for (int j = 0; j < 4; ++j)
                Lf[(mi * 16 + lh * 4 + j) * 264 + col] = acc[mi][ni][j];
    }
    __syncthreads();

    // fully-coalesced out = Lf + x : thread t owns row t>>2, quarter t&3
    {
        const int r = t >> 2, q4 = t & 3;
        const float* xrow = x + (m0r + r) * 256;
        float* orow = out + (m0r + r) * 256;
        const float* lrow = Lf + r * 264;
#pragma unroll
        for (int i = 0; i < 16; ++i) {
            const int c0 = (q4 + 4 * i) * 4;
            const f32x4 lv = *reinterpret_cast<const f32x4*>(lrow + c0);
            const f32x4 xv = *reinterpret_cast<const f32x4*>(xrow + c0);
            f32x4 ov;
#pragma unroll
            for (int j = 0; j < 4; ++j) ov[j] = lv[j] + xv[j];
            *reinterpret_cast<f32x4*>(orow + c0) = ov;
        }
    }
}

// ---------------------------------------------------------------------------
extern "C" void kernel_launch(void* const* d_in, const int* in_sizes, int n_in,
                              void* d_out, int out_size, void* d_ws, size_t ws_size,
                              hipStream_t stream) {
    const float* x   = (const float*)d_in[0];
    const float* gns = (const float*)d_in[1];
    const float* gnb = (const float*)d_in[2];
    const float* Wq  = (const float*)d_in[3];
    const float* bq  = (const float*)d_in[4];
    const float* Wk  = (const float*)d_in[5];
    const float* bk  = (const float*)d_in[6];
    const float* Wv  = (const float*)d_in[7];
    const float* bv  = (const float*)d_in[8];
    const float* Wo  = (const float*)d_in[9];
    const float* bo  = (const float*)d_in[10];
    float* out = (float*)d_out;

    char* ws = (char*)d_ws;
    short* wt   = (short*)(ws);
    float* part = (float*)(ws + 524288);
    const size_t MB16 = 16777216;
    short* qb  = (short*)(ws + (1 << 20));
    short* kb  = (short*)(ws + (1 << 20) + MB16);
    short* vtb = (short*)(ws + (1 << 20) + 2 * MB16);

    hipLaunchKernelGGL(gn_part_prep, dim3(1280), dim3(256), 0, stream,
                       x, part, Wq, Wk, Wv, Wo, wt);
    hipLaunchKernelGGL(qkv_gemm, dim3(512), dim3(256), 0, stream,
                       x, part, gns, gnb, wt, bq, bk, bv, qb, kb, vtb);
    hipLaunchKernelGGL(attn_fused, dim3(256), dim3(512), 0, stream,
                       qb, kb, vtb, wt + 3 * 65536, bo, x, out);
}